// Round 3
// baseline (116.063 us; speedup 1.0000x reference)
//
#include <hip/hip_runtime.h>
#include <math.h>

// Fully fused quanvolution. 36->128 3x3 conv on bf16 MFMA
// (v_mfma_f32_32x32x16_bf16) as 9 shift-GEMMs, ic padded 36->48.
// M enumerated pooling-aligned: m' = cell*4 + sub -> relu+pool in-lane.
// Two images per block, software-pipelined (round-11 structure).
//
// Round-12 changes vs round-11:
//   * actT rows 128 B (64 bf16) with XOR chunk swizzle: data octet o
//     (o = 2ks+hk, ic 8o..8o+7) of LDS row r=(Y,X) lives at 16B-chunk
//     position o ^ h(r), h = (X&1) | (Y&1)<<1 | parity(Y/2 + X/2)<<2.
//     Per mt-instruction the 32 lanes then hit each of the 8 chunks
//     exactly 4x (minimum) -> conv ds_read_b128 conflict-free by
//     construction (was 3.55M extra cycles ~6us on the critical chain).
//     Uniformity needs 4 even + 4 odd cells per mt-tile: the 7 pad slots
//     (cell>48) retarget to cell 0/1 by slot parity. Their clsTT weights
//     are already zero -> prep UNCHANGED.
//   * conv inner loop restructured: af[9] batch per ky-row (9 ds_reads
//     issued ahead of the 9-MFMA cluster), dual accumulators (ky0,2 ->
//     acc0, ky1 -> acc1) break the 27-deep MFMA dependence chain,
//     s_setprio(1) around the MFMA cluster (T5; wave role-diversity now
//     exists between read-batch and MFMA phases).
//   * LDS 72.2 KB -> still 2 blocks/CU; VGPR target <= 256 (no spill).
//
// d_ws:
//   [0, 110592)        bfrag [nt][t*3+ks][lane][8 bf16], zero-padded ic 36..47
//   [110592, +344064)  clsTT fp32 [nt=4][mt=7][q=4][hk=2][l31=32][k12]

typedef __bf16 bf16x8 __attribute__((ext_vector_type(8)));
typedef float  f32x16 __attribute__((ext_vector_type(16)));

union Pack8 { __bf16 h[8]; uint4 v; };

// swizzle hash: pure function of LDS row coords (Y = row>>4, X = row&15)
__device__ __forceinline__ int swz_h(int Y, int X) {
    return (X & 1) | ((Y & 1) << 1) | ((((Y >> 1) + (X >> 1)) & 1) << 2);
}

// one element per thread: 55296 bfrag elems + 86016 clsTT elems (incl. pad)
__global__ __launch_bounds__(256) void prep(
    const float* __restrict__ fus_w,  // (128,36,3,3)
    const float* __restrict__ cls_w,  // (10,6272)
    const float* __restrict__ reg_w,  // (6272)
    __bf16* __restrict__ bfrag,       // 55296 bf16
    float* __restrict__ clsTT)        // 86016 floats
{
    const int gid = blockIdx.x * 256 + threadIdx.x;
    if (gid < 55296) {
        const int j    = gid & 7;
        const int frag = gid >> 3;
        const int lane = frag & 63;
        const int rest = frag >> 6;         // 0..107
        const int m  = rest % 27;           // t*3 + ks
        const int nt = rest / 27;
        const int t  = m / 3, ks = m - t * 3;
        const int n  = nt * 32 + (lane & 31);
        const int ic = ks * 16 + (lane >> 5) * 8 + j;
        const float v = (ic < 36) ? fus_w[n * 324 + ic * 9 + t] : 0.f;
        bfrag[gid] = (__bf16)v;             // consecutive gid -> coalesced store
    } else if (gid < 55296 + 86016) {
        // clsTT element e, kk innermost -> fully coalesced writes
        const int e   = gid - 55296;
        const int kk  = e % 12;
        const int r0  = e / 12;
        const int l31 = r0 & 31;
        const int r1  = r0 >> 5;
        const int hk  = r1 & 1;
        const int r2  = r1 >> 1;
        const int q   = r2 & 3;
        const int r3  = r2 >> 2;
        const int mt  = r3 % 7;
        const int nt  = r3 / 7;
        const int oc   = nt * 32 + l31;
        const int cell = mt * 8 + q * 2 + hk;
        float v = 0.f;
        if (cell < 49 && kk < 11) {
            const int f = oc * 49 + cell;
            v = (kk < 10) ? cls_w[kk * 6272 + f] : reg_w[f];
        }
        clsTT[e] = v;
    }
}

// ---- per-patch producer: depthwise conv + pointwise + quantum -> actT ----
__device__ __forceinline__ void patch_work(
    const int tid, const float* __restrict__ xs, __bf16* __restrict__ actT,
    const float* __restrict__ dw_w, const float* __restrict__ pw_w,
    const float* __restrict__ pw_b, const float* __restrict__ U)
{
    if (tid >= 196) return;
    const int i = tid / 14, j = tid % 14;
    const int Y = 2 * i, X = 2 * j;

    float w9[9];
    #pragma unroll
    for (int t = 0; t < 9; ++t) w9[t] = dw_w[t];
    float dsum = 0.f;
    #pragma unroll
    for (int dy = 0; dy < 2; ++dy) {
        #pragma unroll
        for (int dx = 0; dx < 2; ++dx) {
            const int cy = Y + dy, cx = X + dx;
            #pragma unroll
            for (int ky = 0; ky < 3; ++ky) {
                const int yy = cy + ky - 1;
                if (yy < 0 || yy > 27) continue;
                #pragma unroll
                for (int kx = 0; kx < 3; ++kx) {
                    const int xx = cx + kx - 1;
                    if (xx < 0 || xx > 27) continue;
                    dsum += xs[yy * 28 + xx] * w9[ky * 3 + kx];
                }
            }
        }
    }
    const float dpool = 0.25f * dsum;

    // ds channels 0..31 -> row sp_o, octets 0..3 at swizzled chunk positions
    const int Yr = i + 1, Xr = j + 1;
    const int sp_o = Yr * 16 + Xr;
    const int hb = swz_h(Yr, Xr);
    #pragma unroll
    for (int c8 = 0; c8 < 4; ++c8) {
        Pack8 pk;
        #pragma unroll
        for (int e = 0; e < 8; ++e)
            pk.h[e] = (__bf16)(pw_w[c8 * 8 + e] * dpool + pw_b[c8 * 8 + e]);
        ((uint4*)actT)[sp_o * 8 + (c8 ^ hb)] = pk.v;
    }

    // quantum patch
    const float p0 = xs[Y * 28 + X],       p1 = xs[Y * 28 + X + 1];
    const float p2 = xs[(Y + 1) * 28 + X], p3 = xs[(Y + 1) * 28 + X + 1];
    float c0, s0, c1, s1, c2, s2, c3, s3;
    sincosf(0.5f * p0, &s0, &c0);
    sincosf(0.5f * p1, &s1, &c1);
    sincosf(0.5f * p2, &s2, &c2);
    sincosf(0.5f * p3, &s3, &c3);
    float a01[4] = {c0 * c1, c0 * s1, s0 * c1, s0 * s1};
    float a23[4] = {c2 * c3, c2 * s3, s2 * c3, s2 * s3};
    float amp[16];
    #pragma unroll
    for (int hi = 0; hi < 4; ++hi)
        #pragma unroll
        for (int lo = 0; lo < 4; ++lo)
            amp[hi * 4 + lo] = a01[hi] * a23[lo];

    float meas[4] = {0.f, 0.f, 0.f, 0.f};
    #pragma unroll
    for (int m = 0; m < 16; ++m) {
        float st = 0.f;
        #pragma unroll
        for (int n = 0; n < 16; ++n) st = fmaf(U[m * 16 + n], amp[n], st);
        const float pm = st * st;
        meas[0] += ((m >> 3) & 1) ? -pm : pm;
        meas[1] += ((m >> 2) & 1) ? -pm : pm;
        meas[2] += ((m >> 1) & 1) ? -pm : pm;
        meas[3] += (m & 1) ? -pm : pm;
    }
    const int fbase = i * 56 + j * 4;
    #pragma unroll
    for (int w = 0; w < 4; ++w) {
        const int f  = fbase + w;
        const int ch = f / 196;               // 0..3 -> ic 32+ch
        const int sp = f - ch * 196;
        const int r2 = sp / 14 + 1, c2i = sp % 14 + 1;
        const int sp2 = r2 * 16 + c2i;
        const int hb2 = swz_h(r2, c2i);
        // octet 4 (ic 32..39), element ch, at swizzled chunk position
        actT[sp2 * 64 + ((4 ^ hb2) << 3) + ch] = (__bf16)meas[w];
    }
}

// ---- consumer: 9 shift-GEMMs + in-lane relu/pool + classifier fold ----
__device__ __forceinline__ void conv_fold(
    const __bf16* __restrict__ actT, const bf16x8* __restrict__ bfr,
    const float4* __restrict__ cls4, const float fb_l,
    const int l31, const int hk, float* __restrict__ a11)
{
    for (int mt = 0; mt < 7; ++mt) {
        // lane's A-row: slot = l31>>2 -> cell; dummy slots (cell>48) retarget
        // to cell 0/1 by slot parity (zero classifier weight; keeps the
        // 4-even/4-odd cell split per tile that the swizzle needs)
        const int slot = l31 >> 2;
        int cell = mt * 8 + slot;
        if (cell > 48) cell = (slot & 1);
        const int py = (cell * 9363) >> 16;       // cell/7 for cell<56
        const int px = cell - py * 7;
        const int yy = 2 * py + ((l31 >> 1) & 1);
        const int xx = 2 * px + (l31 & 1);

        f32x16 acc0 = {0.f,0.f,0.f,0.f,0.f,0.f,0.f,0.f,
                       0.f,0.f,0.f,0.f,0.f,0.f,0.f,0.f};
        f32x16 acc1 = {0.f,0.f,0.f,0.f,0.f,0.f,0.f,0.f,
                       0.f,0.f,0.f,0.f,0.f,0.f,0.f,0.f};

        #pragma unroll
        for (int ky = 0; ky < 3; ++ky) {
            const int Yk = yy + ky;
            bf16x8 af[9];
            #pragma unroll
            for (int kx = 0; kx < 3; ++kx) {
                const int Xk = xx + kx;
                const int r  = Yk * 16 + Xk;
                const int hb = swz_h(Yk, Xk);
                const __bf16* rp = actT + r * 64;
                #pragma unroll
                for (int ks = 0; ks < 3; ++ks)
                    af[kx * 3 + ks] =
                        *(const bf16x8*)(rp + (((2 * ks + hk) ^ hb) << 3));
            }
            __builtin_amdgcn_s_setprio(1);
            if (ky == 1) {
                #pragma unroll
                for (int kx = 0; kx < 3; ++kx)
                    #pragma unroll
                    for (int ks = 0; ks < 3; ++ks)
                        acc1 = __builtin_amdgcn_mfma_f32_32x32x16_bf16(
                            af[kx * 3 + ks], bfr[(ky * 3 + kx) * 3 + ks], acc1, 0, 0, 0);
            } else {
                #pragma unroll
                for (int kx = 0; kx < 3; ++kx)
                    #pragma unroll
                    for (int ks = 0; ks < 3; ++ks)
                        acc0 = __builtin_amdgcn_mfma_f32_32x32x16_bf16(
                            af[kx * 3 + ks], bfr[(ky * 3 + kx) * 3 + ks], acc0, 0, 0, 0);
            }
            __builtin_amdgcn_s_setprio(0);
        }

        const float4* cwm = cls4 + mt * 768;      // mt stride: 4*2*32*3 float4
        #pragma unroll
        for (int q = 0; q < 4; ++q) {
            float pv = 0.f;
            #pragma unroll
            for (int s = 0; s < 4; ++s) {
                const float v = acc0[q * 4 + s] + acc1[q * 4 + s] + fb_l;
                pv += (v > 0.f ? v : 0.f);
            }
            pv *= 0.25f;
            const float4 w0 = cwm[q * 192 + 0];
            const float4 w1 = cwm[q * 192 + 1];
            const float4 w2 = cwm[q * 192 + 2];
            a11[0]  = fmaf(pv, w0.x, a11[0]);
            a11[1]  = fmaf(pv, w0.y, a11[1]);
            a11[2]  = fmaf(pv, w0.z, a11[2]);
            a11[3]  = fmaf(pv, w0.w, a11[3]);
            a11[4]  = fmaf(pv, w1.x, a11[4]);
            a11[5]  = fmaf(pv, w1.y, a11[5]);
            a11[6]  = fmaf(pv, w1.z, a11[6]);
            a11[7]  = fmaf(pv, w1.w, a11[7]);
            a11[8]  = fmaf(pv, w2.x, a11[8]);
            a11[9]  = fmaf(pv, w2.y, a11[9]);
            a11[10] = fmaf(pv, w2.z, a11[10]);
        }
    }
}

__global__ __launch_bounds__(256, 2) void quanv_fused(
    const float* __restrict__ x,      // (B,1,28,28)
    const float* __restrict__ dw_w,   // 9
    const float* __restrict__ pw_w,   // 32
    const float* __restrict__ pw_b,   // 32
    const float* __restrict__ U,      // 16x16
    const __bf16* __restrict__ bfrag, // B fragments
    const float* __restrict__ fus_b,  // 128
    const float* __restrict__ clsTT,  // lane-ordered classifier weights
    const float* __restrict__ cls_b,  // 10
    const float* __restrict__ reg_b,  // 1
    float* __restrict__ out,          // B*10 logits, then B aux
    int B)
{
    __shared__ __align__(16) __bf16 actT[2][256 * 64];  // 65,536 B, 128 B rows
    __shared__ float xs[2][784];                        //  6,272 B
    __shared__ float red[2][48];                        //    384 B

    const int b0  = blockIdx.x * 2;
    const int b1  = b0 + 1;
    const bool two = (b1 < B);
    const int tid = threadIdx.x;

    // ---- phase 0: zero both actT buffers, stage both images, hoist bfr ----
    {
        uint4 z; z.x = 0; z.y = 0; z.z = 0; z.w = 0;
        uint4* a4 = (uint4*)&actT[0][0];
        for (int i = tid; i < 4096; i += 256) a4[i] = z;
        const float* xb = x + (size_t)b0 * 784;
        const int tot = two ? 1568 : 784;
        float* xf = &xs[0][0];
        for (int i = tid; i < tot; i += 256) xf[i] = xb[i];
    }

    const int lane = tid & 63, nt = tid >> 6;
    const int l31  = lane & 31, hk = lane >> 5;
    const float fb_l = fus_b[nt * 32 + l31];

    bf16x8 bfr[27];
    {
        const bf16x8* __restrict__ bp = ((const bf16x8*)bfrag) + (nt * 27 * 64 + lane);
        #pragma unroll
        for (int m = 0; m < 27; ++m) bfr[m] = bp[m * 64];
    }

    // classifier weights, float4 view: ((...)*32 + l31)*3 float4s
    const float4* __restrict__ cls4 =
        ((const float4*)clsTT) + ((((nt * 7) * 4) * 2 + hk) * 32 + l31) * 3;

    __syncthreads();

    // ---- pipeline fill: P12(img0) ----
    patch_work(tid, &xs[0][0], &actT[0][0], dw_w, pw_w, pw_b, U);
    __syncthreads();

    // ---- merged steady phase: P12(img1) overlaps P3(img0), no barrier ----
    float a11_0[11];
    #pragma unroll
    for (int k = 0; k < 11; ++k) a11_0[k] = 0.f;
    if (two) patch_work(tid, &xs[1][0], &actT[1][0], dw_w, pw_w, pw_b, U);
    conv_fold(&actT[0][0], bfr, cls4, fb_l, l31, hk, a11_0);
    __syncthreads();

    // ---- pipeline drain: P3(img1) ----
    float a11_1[11];
    #pragma unroll
    for (int k = 0; k < 11; ++k) a11_1[k] = 0.f;
    if (two) conv_fold(&actT[1][0], bfr, cls4, fb_l, l31, hk, a11_1);

    // ---- reduce + output both images ----
    #pragma unroll
    for (int k = 0; k < 11; ++k) {
        float a = a11_0[k];
        float c = a11_1[k];
        #pragma unroll
        for (int off = 32; off > 0; off >>= 1) {
            a += __shfl_down(a, off, 64);
            c += __shfl_down(c, off, 64);
        }
        if (lane == 0) { red[0][k * 4 + nt] = a; red[1][k * 4 + nt] = c; }
    }
    __syncthreads();
    if (tid < 11) {
        const float v = red[0][tid * 4] + red[0][tid * 4 + 1]
                      + red[0][tid * 4 + 2] + red[0][tid * 4 + 3];
        if (tid < 10) out[b0 * 10 + tid] = v + cls_b[tid];
        else          out[B * 10 + b0]   = v + reg_b[0];
    } else if (two && tid >= 64 && tid < 75) {
        const int k = tid - 64;
        const float v = red[1][k * 4] + red[1][k * 4 + 1]
                      + red[1][k * 4 + 2] + red[1][k * 4 + 3];
        if (k < 10) out[b1 * 10 + k] = v + cls_b[k];
        else        out[B * 10 + b1] = v + reg_b[0];
    }
}

extern "C" void kernel_launch(void* const* d_in, const int* in_sizes, int n_in,
                              void* d_out, int out_size, void* d_ws, size_t ws_size,
                              hipStream_t stream) {
    const float* x    = (const float*)d_in[0];
    const float* dw_w = (const float*)d_in[1];
    const float* pw_w = (const float*)d_in[2];
    const float* pw_b = (const float*)d_in[3];
    const float* U    = (const float*)d_in[4];
    const float* fw   = (const float*)d_in[5];
    const float* fb   = (const float*)d_in[6];
    const float* cw   = (const float*)d_in[7];
    const float* cb   = (const float*)d_in[8];
    const float* rw   = (const float*)d_in[9];
    const float* rb   = (const float*)d_in[10];
    const int B = in_sizes[0] / 784;

    __bf16* bfrag = (__bf16*)d_ws;                    // 110,592 B
    float*  clsTT = (float*)((char*)d_ws + 110592);   // 344,064 B

    prep<<<(55296 + 86016 + 255) / 256, 256, 0, stream>>>(fw, cw, rw, bfrag, clsTT);
    const int nblk = (B + 1) / 2;
    quanv_fused<<<nblk, 256, 0, stream>>>(x, dw_w, pw_w, pw_b, U, bfrag, fb,
                                          clsTT, cb, rb, (float*)d_out, B);
}

// Round 4
// 108.171 us; speedup vs baseline: 1.0730x; 1.0730x over previous
//
#include <hip/hip_runtime.h>
#include <math.h>

// Fully fused quanvolution. 36->128 3x3 conv on bf16 MFMA
// (v_mfma_f32_32x32x16_bf16) as shift-GEMMs. Two images per block,
// software-pipelined (round-11 structure).
//
// Round-13 changes vs round-11 (round-12 swizzle/batch/setprio REVERTED -
// it regressed 44.5->60.5us and didn't move the conflict counter):
//   * K-packing: ic padding 36->48 made the ks=2 K-slice 3/4 zeros (only
//     4 quantum channels real) yet it cost 9/27 MFMAs + 9/27 b128 reads
//     per mt. Now: dense pointwise channels ic0-31 as 18 tap-wise MFMAs
//     (ks 0,1), quantum channels packed K-wise across taps: K index =
//     (tap,ch), 3 slices of K=16 cover taps 0-11 (9-11 zero weight).
//     21 MFMA/mt (-22%), 18 b128 + 5 b64 LDS reads/mt (~-24% LDS cycles).
//   * Quantum activations live in a tiny Q tile [256 rows][4 ch] bf16
//     (2KB/img), read as b64 pairs; zero-B tail taps make A don't-cares.
//   * actT narrows to 40-elem (80B) rows: stride 5 chunks, 5 coprime 8,
//     no pow2 resonance. LDS 51.7KB. bfr hoist 27->21 frags (-24 VGPR).
//
// d_ws:
//   [0, 86016)        bfrag [nt][21 frags][lane][8 bf16]
//                       frags 0..17: t*2+ks (ic = ks*16+hk*8+j)
//                       frags 18..20: packed quantum (k=(tap,ch))
//   [86016, +344064)  clsTT fp32 [nt=4][mt=7][q=4][hk=2][l31=32][k12]

typedef __bf16 bf16x8 __attribute__((ext_vector_type(8)));
typedef __bf16 bf16x4 __attribute__((ext_vector_type(4)));
typedef float  f32x16 __attribute__((ext_vector_type(16)));

union Pack8 { __bf16 h[8]; uint4 v; };
union QPair { struct { bf16x4 lo, hi; } p; bf16x8 v; };

// one element per thread: 43008 bfrag elems + 86016 clsTT elems (incl. pad)
__global__ __launch_bounds__(256) void prep(
    const float* __restrict__ fus_w,  // (128,36,3,3)
    const float* __restrict__ cls_w,  // (10,6272)
    const float* __restrict__ reg_w,  // (6272)
    __bf16* __restrict__ bfrag,       // 43008 bf16
    float* __restrict__ clsTT)        // 86016 floats
{
    const int gid = blockIdx.x * 256 + threadIdx.x;
    if (gid < 43008) {
        const int j    = gid & 7;
        const int frag = gid >> 3;
        const int lane = frag & 63;
        const int rest = frag >> 6;         // 0..83
        const int m  = rest % 21;
        const int nt = rest / 21;
        const int n  = nt * 32 + (lane & 31);
        const int hk = lane >> 5;
        float v;
        if (m < 18) {
            const int t = m >> 1, ks = m & 1;
            const int ic = ks * 16 + hk * 8 + j;        // 0..31, all real
            v = fus_w[n * 324 + ic * 9 + t];
        } else {
            const int ps = m - 18;
            const int k  = hk * 8 + j;                  // 0..15
            const int tap = ps * 4 + (k >> 2);          // 0..11
            const int ch  = k & 3;
            v = (tap < 9) ? fus_w[n * 324 + (32 + ch) * 9 + tap] : 0.f;
        }
        bfrag[gid] = (__bf16)v;             // consecutive gid -> coalesced store
    } else if (gid < 43008 + 86016) {
        // clsTT element e, kk innermost -> fully coalesced writes
        const int e   = gid - 43008;
        const int kk  = e % 12;
        const int r0  = e / 12;
        const int l31 = r0 & 31;
        const int r1  = r0 >> 5;
        const int hk  = r1 & 1;
        const int r2  = r1 >> 1;
        const int q   = r2 & 3;
        const int r3  = r2 >> 2;
        const int mt  = r3 % 7;
        const int nt  = r3 / 7;
        const int oc   = nt * 32 + l31;
        const int cell = mt * 8 + q * 2 + hk;
        float v = 0.f;
        if (cell < 49 && kk < 11) {
            const int f = oc * 49 + cell;
            v = (kk < 10) ? cls_w[kk * 6272 + f] : reg_w[f];
        }
        clsTT[e] = v;
    }
}

// ---- per-patch producer: depthwise conv + pointwise + quantum -> actT,Q ----
__device__ __forceinline__ void patch_work(
    const int tid, const float* __restrict__ xs, __bf16* __restrict__ actT,
    __bf16* __restrict__ Qt,
    const float* __restrict__ dw_w, const float* __restrict__ pw_w,
    const float* __restrict__ pw_b, const float* __restrict__ U)
{
    if (tid >= 196) return;
    const int i = tid / 14, j = tid % 14;
    const int Y = 2 * i, X = 2 * j;

    float w9[9];
    #pragma unroll
    for (int t = 0; t < 9; ++t) w9[t] = dw_w[t];
    float dsum = 0.f;
    #pragma unroll
    for (int dy = 0; dy < 2; ++dy) {
        #pragma unroll
        for (int dx = 0; dx < 2; ++dx) {
            const int cy = Y + dy, cx = X + dx;
            #pragma unroll
            for (int ky = 0; ky < 3; ++ky) {
                const int yy = cy + ky - 1;
                if (yy < 0 || yy > 27) continue;
                #pragma unroll
                for (int kx = 0; kx < 3; ++kx) {
                    const int xx = cx + kx - 1;
                    if (xx < 0 || xx > 27) continue;
                    dsum += xs[yy * 28 + xx] * w9[ky * 3 + kx];
                }
            }
        }
    }
    const float dpool = 0.25f * dsum;

    // ds channels 0..31 -> row sp_o, chunks 0..3 of 5 (80B row stride)
    const int sp_o = (i + 1) * 16 + (j + 1);
    #pragma unroll
    for (int c8 = 0; c8 < 4; ++c8) {
        Pack8 pk;
        #pragma unroll
        for (int e = 0; e < 8; ++e)
            pk.h[e] = (__bf16)(pw_w[c8 * 8 + e] * dpool + pw_b[c8 * 8 + e]);
        ((uint4*)actT)[sp_o * 5 + c8] = pk.v;
    }

    // quantum patch
    const float p0 = xs[Y * 28 + X],       p1 = xs[Y * 28 + X + 1];
    const float p2 = xs[(Y + 1) * 28 + X], p3 = xs[(Y + 1) * 28 + X + 1];
    float c0, s0, c1, s1, c2, s2, c3, s3;
    sincosf(0.5f * p0, &s0, &c0);
    sincosf(0.5f * p1, &s1, &c1);
    sincosf(0.5f * p2, &s2, &c2);
    sincosf(0.5f * p3, &s3, &c3);
    float a01[4] = {c0 * c1, c0 * s1, s0 * c1, s0 * s1};
    float a23[4] = {c2 * c3, c2 * s3, s2 * c3, s2 * s3};
    float amp[16];
    #pragma unroll
    for (int hi = 0; hi < 4; ++hi)
        #pragma unroll
        for (int lo = 0; lo < 4; ++lo)
            amp[hi * 4 + lo] = a01[hi] * a23[lo];

    float meas[4] = {0.f, 0.f, 0.f, 0.f};
    #pragma unroll
    for (int m = 0; m < 16; ++m) {
        float st = 0.f;
        #pragma unroll
        for (int n = 0; n < 16; ++n) st = fmaf(U[m * 16 + n], amp[n], st);
        const float pm = st * st;
        meas[0] += ((m >> 3) & 1) ? -pm : pm;
        meas[1] += ((m >> 2) & 1) ? -pm : pm;
        meas[2] += ((m >> 1) & 1) ? -pm : pm;
        meas[3] += (m & 1) ? -pm : pm;
    }
    const int fbase = i * 56 + j * 4;
    #pragma unroll
    for (int w = 0; w < 4; ++w) {
        const int f  = fbase + w;
        const int ch = f / 196;               // 0..3 -> quantum chan
        const int sp = f - ch * 196;
        const int r2 = sp / 14 + 1, c2i = sp % 14 + 1;
        const int sp2 = r2 * 16 + c2i;
        Qt[sp2 * 4 + ch] = (__bf16)meas[w];
    }
}

// ---- consumer: 21 shift-GEMMs + in-lane relu/pool + classifier fold ----
__device__ __forceinline__ void conv_fold(
    const __bf16* __restrict__ actT, const __bf16* __restrict__ Qt,
    const bf16x8* __restrict__ bfr, const float4* __restrict__ cls4,
    const float fb_l, const int l31, const int hk,
    const int* __restrict__ offL, const int* __restrict__ offH,
    float* __restrict__ a11)
{
    for (int mt = 0; mt < 7; ++mt) {
        // lane's A-row: m' = mt*32 + l31 -> pooled cell + sub-pixel
        const int mp   = mt * 32 + l31;
        const int cell = mp >> 2;
        const int cc = (cell < 49) ? cell : 48;   // clamp garbage rows in-bounds
        const int py = (cc * 9363) >> 16;         // cc/7 for cc<56
        const int px = cc - py * 7;
        const int yy = 2 * py + ((mp >> 1) & 1);
        const int xx = 2 * px + (mp & 1);
        const int rowbase = yy * 16 + xx;

        f32x16 acc = {0.f,0.f,0.f,0.f,0.f,0.f,0.f,0.f,
                      0.f,0.f,0.f,0.f,0.f,0.f,0.f,0.f};

        #pragma unroll
        for (int t = 0; t < 9; ++t) {
            const int ky = t / 3, kx = t - ky * 3;
            const int row = rowbase + ky * 16 + kx;
            const __bf16* rp = actT + row * 40 + hk * 8;
            #pragma unroll
            for (int ks = 0; ks < 2; ++ks) {
                const bf16x8 af = *(const bf16x8*)(rp + ks * 16);
                acc = __builtin_amdgcn_mfma_f32_32x32x16_bf16(af, bfr[t * 2 + ks],
                                                              acc, 0, 0, 0);
            }
        }
        // packed quantum slices: K = (tap,ch); B rows for taps>8 are zero
        #pragma unroll
        for (int ps = 0; ps < 3; ++ps) {
            QPair u;
            u.p.lo = *(const bf16x4*)(Qt + (rowbase + offL[ps]) * 4);
            u.p.hi = *(const bf16x4*)(Qt + (rowbase + offH[ps]) * 4);
            acc = __builtin_amdgcn_mfma_f32_32x32x16_bf16(u.v, bfr[18 + ps],
                                                          acc, 0, 0, 0);
        }

        // epilogue: relu+pool in-lane; classifier fold, 3x dwordx4 per q
        const float4* cwm = cls4 + mt * 768;      // mt stride: 4*2*32*3 float4
        #pragma unroll
        for (int q = 0; q < 4; ++q) {
            float pv = 0.f;
            #pragma unroll
            for (int s = 0; s < 4; ++s) {
                const float v = acc[q * 4 + s] + fb_l;
                pv += (v > 0.f ? v : 0.f);
            }
            pv *= 0.25f;
            const float4 w0 = cwm[q * 192 + 0];
            const float4 w1 = cwm[q * 192 + 1];
            const float4 w2 = cwm[q * 192 + 2];
            a11[0]  = fmaf(pv, w0.x, a11[0]);
            a11[1]  = fmaf(pv, w0.y, a11[1]);
            a11[2]  = fmaf(pv, w0.z, a11[2]);
            a11[3]  = fmaf(pv, w0.w, a11[3]);
            a11[4]  = fmaf(pv, w1.x, a11[4]);
            a11[5]  = fmaf(pv, w1.y, a11[5]);
            a11[6]  = fmaf(pv, w1.z, a11[6]);
            a11[7]  = fmaf(pv, w1.w, a11[7]);
            a11[8]  = fmaf(pv, w2.x, a11[8]);
            a11[9]  = fmaf(pv, w2.y, a11[9]);
            a11[10] = fmaf(pv, w2.z, a11[10]);
        }
    }
}

__global__ __launch_bounds__(256, 2) void quanv_fused(
    const float* __restrict__ x,      // (B,1,28,28)
    const float* __restrict__ dw_w,   // 9
    const float* __restrict__ pw_w,   // 32
    const float* __restrict__ pw_b,   // 32
    const float* __restrict__ U,      // 16x16
    const __bf16* __restrict__ bfrag, // B fragments
    const float* __restrict__ fus_b,  // 128
    const float* __restrict__ clsTT,  // lane-ordered classifier weights
    const float* __restrict__ cls_b,  // 10
    const float* __restrict__ reg_b,  // 1
    float* __restrict__ out,          // B*10 logits, then B aux
    int B)
{
    __shared__ __align__(16) __bf16 actT[2][256 * 40];  // 40,960 B, 80 B rows
    __shared__ __align__(16) __bf16 Qt[2][256 * 4];     //  4,096 B
    __shared__ float xs[2][784];                        //  6,272 B
    __shared__ float red[2][48];                        //    384 B

    const int b0  = blockIdx.x * 2;
    const int b1  = b0 + 1;
    const bool two = (b1 < B);
    const int tid = threadIdx.x;

    // ---- phase 0: zero actT+Qt (halo stays zero), stage images, hoist bfr ----
    {
        uint4 z; z.x = 0; z.y = 0; z.z = 0; z.w = 0;
        uint4* a4 = (uint4*)&actT[0][0];
        for (int i = tid; i < 2560; i += 256) a4[i] = z;
        uint4* q4 = (uint4*)&Qt[0][0];
        for (int i = tid; i < 256; i += 256) q4[i] = z;
        const float* xb = x + (size_t)b0 * 784;
        const int tot = two ? 1568 : 784;
        float* xf = &xs[0][0];
        for (int i = tid; i < tot; i += 256) xf[i] = xb[i];
    }

    const int lane = tid & 63, nt = tid >> 6;
    const int l31  = lane & 31, hk = lane >> 5;
    const float fb_l = fus_b[nt * 32 + l31];

    bf16x8 bfr[21];
    {
        const bf16x8* __restrict__ bp = ((const bf16x8*)bfrag) + (nt * 21 * 64 + lane);
        #pragma unroll
        for (int m = 0; m < 21; ++m) bfr[m] = bp[m * 64];
    }

    // per-lane-half tap offsets for the packed quantum slices
    int offL[3], offH[3];
    #pragma unroll
    for (int ps = 0; ps < 3; ++ps) {
        int tL = ps * 4 + hk * 2;
        int tH = tL + 1;
        if (tL > 8) tL = 0;       // zero-B tail: A value is a don't-care
        if (tH > 8) tH = 0;
        offL[ps] = (tL / 3) * 16 + (tL % 3);
        offH[ps] = (tH / 3) * 16 + (tH % 3);
    }

    // classifier weights, float4 view: ((...)*32 + l31)*3 float4s
    const float4* __restrict__ cls4 =
        ((const float4*)clsTT) + ((((nt * 7) * 4) * 2 + hk) * 32 + l31) * 3;

    __syncthreads();

    // ---- pipeline fill: P12(img0) ----
    patch_work(tid, &xs[0][0], &actT[0][0], &Qt[0][0], dw_w, pw_w, pw_b, U);
    __syncthreads();

    // ---- merged steady phase: P12(img1) overlaps P3(img0), no barrier ----
    float a11_0[11];
    #pragma unroll
    for (int k = 0; k < 11; ++k) a11_0[k] = 0.f;
    if (two) patch_work(tid, &xs[1][0], &actT[1][0], &Qt[1][0], dw_w, pw_w, pw_b, U);
    conv_fold(&actT[0][0], &Qt[0][0], bfr, cls4, fb_l, l31, hk, offL, offH, a11_0);
    __syncthreads();

    // ---- pipeline drain: P3(img1) ----
    float a11_1[11];
    #pragma unroll
    for (int k = 0; k < 11; ++k) a11_1[k] = 0.f;
    if (two) conv_fold(&actT[1][0], &Qt[1][0], bfr, cls4, fb_l, l31, hk, offL, offH, a11_1);

    // ---- reduce + output both images ----
    #pragma unroll
    for (int k = 0; k < 11; ++k) {
        float a = a11_0[k];
        float c = a11_1[k];
        #pragma unroll
        for (int off = 32; off > 0; off >>= 1) {
            a += __shfl_down(a, off, 64);
            c += __shfl_down(c, off, 64);
        }
        if (lane == 0) { red[0][k * 4 + nt] = a; red[1][k * 4 + nt] = c; }
    }
    __syncthreads();
    if (tid < 11) {
        const float v = red[0][tid * 4] + red[0][tid * 4 + 1]
                      + red[0][tid * 4 + 2] + red[0][tid * 4 + 3];
        if (tid < 10) out[b0 * 10 + tid] = v + cls_b[tid];
        else          out[B * 10 + b0]   = v + reg_b[0];
    } else if (two && tid >= 64 && tid < 75) {
        const int k = tid - 64;
        const float v = red[1][k * 4] + red[1][k * 4 + 1]
                      + red[1][k * 4 + 2] + red[1][k * 4 + 3];
        if (k < 10) out[b1 * 10 + k] = v + cls_b[k];
        else        out[B * 10 + b1] = v + reg_b[0];
    }
}

extern "C" void kernel_launch(void* const* d_in, const int* in_sizes, int n_in,
                              void* d_out, int out_size, void* d_ws, size_t ws_size,
                              hipStream_t stream) {
    const float* x    = (const float*)d_in[0];
    const float* dw_w = (const float*)d_in[1];
    const float* pw_w = (const float*)d_in[2];
    const float* pw_b = (const float*)d_in[3];
    const float* U    = (const float*)d_in[4];
    const float* fw   = (const float*)d_in[5];
    const float* fb   = (const float*)d_in[6];
    const float* cw   = (const float*)d_in[7];
    const float* cb   = (const float*)d_in[8];
    const float* rw   = (const float*)d_in[9];
    const float* rb   = (const float*)d_in[10];
    const int B = in_sizes[0] / 784;

    __bf16* bfrag = (__bf16*)d_ws;                   // 86,016 B
    float*  clsTT = (float*)((char*)d_ws + 86016);   // 344,064 B

    prep<<<(43008 + 86016 + 255) / 256, 256, 0, stream>>>(fw, cw, rw, bfrag, clsTT);
    const int nblk = (B + 1) / 2;
    quanv_fused<<<nblk, 256, 0, stream>>>(x, dw_w, pw_w, pw_b, U, bfrag, fb,
                                          clsTT, cb, rb, (float*)d_out, B);
}